// Round 9
// baseline (293.112 us; speedup 1.0000x reference)
//
#include <hip/hip_runtime.h>
#include <hip/hip_bf16.h>
#include <hip/hip_fp16.h>

#define FDIM 64

// Bucketed CSR build parameters
#define NBLK_G 256        // chunks per layer for p1
#define CHUNK_CAP 8192    // max edges per chunk block (32 KB LDS stage)
#define BKT_SHIFT 7
#define BKT_NODES 128     // dest nodes per bucket
#define BINS 256          // BKT_NODES x 2 source-halves (R9)
#define NB_MAX 512        // max buckets (N <= 65536)
#define STCAP 8192        // P4 LDS stage cap (edges)

__device__ __forceinline__ int clampi(int v, int n) { return min(max(v, 0), n - 1); }

// ---- P1 (both layers): block-local bin + contiguous stage + counts --------
// grid = 2*NBLK_G; blocks [0,NBLK_G) do layer 0, rest layer 1. (R7-verified)
// Accumulates global bucketTot via atomics; bucketTot zeroed before launch.
__global__ __launch_bounds__(512) void p1_bin_stage(
    const int* __restrict__ r0, const int* __restrict__ c0,
    const int* __restrict__ r1, const int* __restrict__ c1,
    unsigned* __restrict__ pairs1, int* __restrict__ blockcnt,
    int* __restrict__ startsTbl, int* __restrict__ bucketTot,
    int n, int E, int nb, int chunk)
{
    __shared__ unsigned stage[CHUNK_CAP];
    __shared__ int hist[NB_MAX];
    __shared__ int curs[NB_MAX];
    int layer = blockIdx.x / NBLK_G;
    int cb = blockIdx.x - layer * NBLK_G;
    const int* rows = layer ? r1 : r0;
    const int* cols = layer ? c1 : c0;
    pairs1    += (size_t)layer * E;
    blockcnt  += (size_t)layer * NBLK_G * nb;
    startsTbl += (size_t)layer * NBLK_G * nb;
    bucketTot += layer * nb;

    int tid = threadIdx.x;
    int base = cb * chunk;
    int cnt = E - base; if (cnt > chunk) cnt = chunk; if (cnt < 0) cnt = 0;
    for (int i = tid; i < NB_MAX; i += 512) hist[i] = 0;
    __syncthreads();
    for (int i = tid; i < cnt; i += 512)
        atomicAdd(&hist[clampi(cols[base + i], n) >> BKT_SHIFT], 1);
    __syncthreads();
    for (int b = tid; b < nb; b += 512) {
        int hv = hist[b];
        blockcnt[cb * nb + b] = hv;
        if (hv) atomicAdd(&bucketTot[b], hv);   // global bucket totals
    }
    __syncthreads();
    for (int off = 1; off < NB_MAX; off <<= 1) {
        int t = (tid >= off) ? hist[tid - off] : 0;
        __syncthreads();
        hist[tid] += t;
        __syncthreads();
    }
    curs[tid] = (tid == 0) ? 0 : hist[tid - 1];
    __syncthreads();
    // persist chunk-local exclusive starts BEFORE atomics mutate curs
    for (int b = tid; b < nb; b += 512) startsTbl[cb * nb + b] = curs[b];
    __syncthreads();
    for (int i = tid; i < cnt; i += 512) {
        int c = clampi(cols[base + i], n);
        int r = clampi(rows[base + i], n);
        int p = atomicAdd(&curs[c >> BKT_SHIFT], 1);
        stage[p] = ((unsigned)r << 16) | (unsigned)c;
    }
    __syncthreads();
    for (int i = tid; i < cnt; i += 512) pairs1[base + i] = stage[i];
}

// ---- P4 (both layers, 512 threads): per-bucket fine CSR --------------------
// R9: bins keyed by (local node, src>=halfN) -> 256 bins, so each node gets
// TWO contiguous segments ordered by source half: rowptr[2n]..rowptr[2n+1]
// (lower-half sources) and ..rowptr[2n+2] (upper). Enables the source-tiled
// L2-resident gather. rowptr is [2n+1] ints per layer.
__global__ __launch_bounds__(512) void p4_fine2(
    const unsigned* __restrict__ pairs1, const int* __restrict__ blockcnt,
    const int* __restrict__ startsTbl, const int* __restrict__ bucketTot,
    int* __restrict__ rowptr, unsigned short* __restrict__ csridx,
    int n, int E, int nb, int chunk, int nblk, int halfN)
{
    __shared__ unsigned st[STCAP];
    __shared__ int h[BINS];
    __shared__ int cur[BINS];
    __shared__ int bscan[NB_MAX];    // inclusive scan of bucketTot (512 wide)
    __shared__ int colv[NBLK_G];     // inclusive scan of this bucket's column
    int tid = threadIdx.x;
    int layer = blockIdx.x / nb;
    int b = blockIdx.x - layer * nb;
    pairs1    += (size_t)layer * E;
    blockcnt  += (size_t)layer * NBLK_G * nb;
    startsTbl += (size_t)layer * NBLK_G * nb;
    bucketTot += layer * nb;
    rowptr    += (size_t)layer * (2 * n + 1);
    csridx    += (size_t)layer * E;

    bscan[tid] = (tid < nb) ? bucketTot[tid] : 0;
    if (tid < NBLK_G) {
        int myc = (tid < nblk) ? blockcnt[(size_t)tid * nb + b] : 0;
        colv[tid] = myc;
    }
    if (tid < BINS) h[tid] = 0;
    __syncthreads();
    // fused Hillis-Steele: 512-wide on bscan, 256-wide on colv
    for (int off = 1; off < NB_MAX; off <<= 1) {
        int t0 = (tid >= off) ? bscan[tid - off] : 0;
        int t2 = (tid < NBLK_G && off < NBLK_G && tid >= off) ? colv[tid - off] : 0;
        __syncthreads();
        bscan[tid] += t0;
        if (tid < NBLK_G && off < NBLK_G) colv[tid] += t2;
        __syncthreads();
    }
    int beg = (b == 0) ? 0 : bscan[b - 1];
    int cnt = bscan[b] - beg;

    bool fit = (cnt <= STCAP);       // block-uniform -> in-branch barriers legal
    if (fit) {
        // 2 threads per chunk: tid&255 = chunk, tid>>8 = half
        int ch = tid & (NBLK_G - 1);
        int half = tid >> 8;
        if (ch < nblk) {
            int ccnt = E - ch * chunk; if (ccnt > chunk) ccnt = chunk; if (ccnt < 0) ccnt = 0;
            int stt = startsTbl[(size_t)ch * nb + b];
            int enn = (b + 1 < nb) ? startsTbl[(size_t)ch * nb + b + 1] : ccnt;
            int len = enn - stt;
            int dst = (ch == 0) ? 0 : colv[ch - 1];      // exclusive offset
            int h0 = (len + 1) >> 1;
            int jb = half ? (stt + h0) : stt;
            int je = half ? enn : (stt + h0);
            int db = half ? (dst + h0) : dst;
            const unsigned* srcp = pairs1 + (size_t)ch * chunk;
            for (int j = jb; j < je; ++j)
                st[db + (j - jb)] = srcp[j];
        }
        __syncthreads();
        for (int i = tid; i < cnt; i += 512) {
            unsigned pk = st[i];
            int key = (((int)pk & (BKT_NODES - 1)) << 1) |
                      ((int)(pk >> 16) >= halfN);
            atomicAdd(&h[key], 1);
        }
    } else {
        for (int i = tid; i < nblk; i += 512) {
            int ccnt = E - i * chunk; if (ccnt > chunk) ccnt = chunk; if (ccnt < 0) ccnt = 0;
            int stt = startsTbl[(size_t)i * nb + b];
            int enn = (b + 1 < nb) ? startsTbl[(size_t)i * nb + b + 1] : ccnt;
            for (int j = stt; j < enn; ++j) {
                unsigned pk = pairs1[(size_t)i * chunk + j];
                int key = (((int)pk & (BKT_NODES - 1)) << 1) |
                          ((int)(pk >> 16) >= halfN);
                atomicAdd(&h[key], 1);
            }
        }
    }
    // barrier between histogram atomics and scan (round-9 race fix)
    __syncthreads();
    for (int off = 1; off < BINS; off <<= 1) {
        int t = (tid >= off && tid < BINS) ? h[tid - off] : 0;
        __syncthreads();
        if (tid < BINS) h[tid] += t;
        __syncthreads();
    }
    if (tid < BINS) {
        int ln = tid >> 1;               // local node; tid&1 = source half
        int node = b * BKT_NODES + ln;
        int startl = (tid == 0) ? 0 : h[tid - 1];
        cur[tid] = startl;
        if (node < n) rowptr[2 * node + (tid & 1)] = beg + startl;
    }
    __syncthreads();
    if (fit) {
        for (int i = tid; i < cnt; i += 512) {
            unsigned pk = st[i];
            int key = (((int)pk & (BKT_NODES - 1)) << 1) |
                      ((int)(pk >> 16) >= halfN);
            int p = atomicAdd(&cur[key], 1);
            csridx[beg + p] = (unsigned short)(pk >> 16);
        }
    } else {
        for (int i = tid; i < nblk; i += 512) {
            int ccnt = E - i * chunk; if (ccnt > chunk) ccnt = chunk; if (ccnt < 0) ccnt = 0;
            int stt = startsTbl[(size_t)i * nb + b];
            int enn = (b + 1 < nb) ? startsTbl[(size_t)i * nb + b + 1] : ccnt;
            for (int j = stt; j < enn; ++j) {
                unsigned pk = pairs1[(size_t)i * chunk + j];
                int key = (((int)pk & (BKT_NODES - 1)) << 1) |
                          ((int)(pk >> 16) >= halfN);
                int p = atomicAdd(&cur[key], 1);
                csridx[beg + p] = (unsigned short)(pk >> 16);
            }
        }
    }
    if (b == nb - 1 && tid == 0) rowptr[2 * n] = E;
}

// ------ GEMM precompute: P = src@W (fp16), Q = src@R + b (fp32) -------------
// mean-agg is linear, so agg(x)@W == agg(x@W). Weights register-resident;
// per-row broadcast via v_readlane. Q32 may alias src (wave reads its row
// before writing; rows are wave-disjoint).
__global__ __launch_bounds__(256) void gemm_pq_kernel(
    const float* __restrict__ src, const float* __restrict__ W,
    const float* __restrict__ R, const float* __restrict__ bvec,
    __half* __restrict__ P16, float* __restrict__ Q32, int n)
{
    int lane = threadIdx.x & 63;
    int wv = threadIdx.x >> 6;
    float wcol[FDIM], rcol[FDIM];
#pragma unroll
    for (int k = 0; k < FDIM; ++k) {
        wcol[k] = W[k * FDIM + lane];   // coalesced: lane j reads W[k][j]
        rcol[k] = R[k * FDIM + lane];
    }
    float bj = bvec[lane];
    for (int row = blockIdx.x * 4 + wv; row < n; row += gridDim.x * 4) {
        float xv = src[((size_t)row << 6) + lane];
        float accP = 0.0f, accQ = bj;
#pragma unroll
        for (int k = 0; k < FDIM; ++k) {
            float s = __uint_as_float(
                __builtin_amdgcn_readlane(__float_as_uint(xv), k));
            accP = fmaf(s, wcol[k], accP);
            accQ = fmaf(s, rcol[k], accQ);
        }
        P16[((size_t)row << 6) + lane] = __float2half(accP);
        Q32[((size_t)row << 6) + lane] = accQ;
    }
}

// ------ Source-tiled fused gather (R9) --------------------------------------
// PASS 0: gathers the node's lower-half-source segment (rows < halfN; that
//   3.2 MB table half is L2-resident per XCD) and adds sumA*dinv into out32
//   WITHOUT activation. PASS 1: upper-half segment, adds sumB*dinv, applies
//   relu/norm, writes final. dinv uses the full degree rowptr[2n+2]-rowptr[2n].
// Inner loop keeps R8's batched 4x{shfl,load} form.
template <int PASS, bool RELU, bool NORM>
__global__ __launch_bounds__(256) void fused_gather_kernel(
    const int* __restrict__ rowptr, const unsigned short* __restrict__ csridx,
    const __half* __restrict__ P16, float* __restrict__ out32, int n)
{
    __shared__ __align__(16) float aRow[4][FDIM];
    int tid = threadIdx.x;
    int lane = tid & 63, w = tid >> 6;
    int g = lane >> 3;        // edge sub-group 0..7
    int q = lane & 7;         // 8-feature chunk within row

    for (int node = blockIdx.x * 4 + w; node < n; node += gridDim.x * 4) {
        int p0 = rowptr[2 * node], p1 = rowptr[2 * node + 1],
            p2 = rowptr[2 * node + 2];
        int beg = PASS ? p1 : p0;
        int end = PASS ? p2 : p1;
        float dinv = 1.0f / fmaxf((float)(p2 - p0), 1.0f);
        float ownv = out32[((size_t)node << 6) + lane];   // Q or pass-0 partial
        float s0 = 0.f, s1 = 0.f, s2 = 0.f, s3 = 0.f,
              s4 = 0.f, s5 = 0.f, s6 = 0.f, s7 = 0.f;
        for (int base = beg; base < end; base += 64) {
            int cnt = end - base; if (cnt > 64) cnt = 64;
            int ei = base + lane;
            int myidx = (ei < end) ? (int)csridx[ei] : 0;
            for (int t4 = 0; t4 < 64; t4 += 32) {
                if (t4 >= cnt) break;
                int sidx[4];
                float4 v[4];
#pragma unroll
                for (int u = 0; u < 4; ++u)
                    sidx[u] = __shfl(myidx, t4 | (u << 3) | g, 64);
#pragma unroll
                for (int u = 0; u < 4; ++u) {
                    int e = t4 | (u << 3) | g;
                    v[u] = make_float4(0.f, 0.f, 0.f, 0.f);
                    if (e < cnt)
                        v[u] = *((const float4*)(P16 + ((size_t)sidx[u] << 6)) + q);
                }
#pragma unroll
                for (int u = 0; u < 4; ++u) {
                    const __half2* hp = (const __half2*)&v[u];
                    float2 f0 = __half22float2(hp[0]);
                    float2 f1 = __half22float2(hp[1]);
                    float2 f2 = __half22float2(hp[2]);
                    float2 f3 = __half22float2(hp[3]);
                    s0 += f0.x; s1 += f0.y; s2 += f1.x; s3 += f1.y;
                    s4 += f2.x; s5 += f2.y; s6 += f3.x; s7 += f3.y;
                }
            }
        }
#pragma unroll
        for (int o = 8; o < 64; o <<= 1) {
            s0 += __shfl_xor(s0, o, 64);
            s1 += __shfl_xor(s1, o, 64);
            s2 += __shfl_xor(s2, o, 64);
            s3 += __shfl_xor(s3, o, 64);
            s4 += __shfl_xor(s4, o, 64);
            s5 += __shfl_xor(s5, o, 64);
            s6 += __shfl_xor(s6, o, 64);
            s7 += __shfl_xor(s7, o, 64);
        }
        if (g == 0) {
            float4* ar = (float4*)&aRow[w][q * 8];
            ar[0] = make_float4(s0 * dinv, s1 * dinv, s2 * dinv, s3 * dinv);
            ar[1] = make_float4(s4 * dinv, s5 * dinv, s6 * dinv, s7 * dinv);
        }
        // wave-local LDS RAW: ordered within the wave, no barrier needed
        float acc = aRow[w][lane] + ownv;
        if (PASS == 1) {
            if (RELU) acc = fmaxf(acc, 0.0f);
            if (NORM) {
                float ss = acc * acc;
#pragma unroll
                for (int o = 32; o; o >>= 1) ss += __shfl_xor(ss, o, 64);
                acc *= 1.0f / fmaxf(sqrtf(ss), 1e-12f);
            }
        }
        out32[((size_t)node << 6) + lane] = acc;
    }
}

// ----------------- Atomic scatter path (fallback, 13.0 MB ws) ---------------
__global__ __launch_bounds__(256) void scatter_kernel(
    const float* __restrict__ src, const int* __restrict__ rows, const int* __restrict__ cols,
    float* __restrict__ agg, float* __restrict__ deg, int n, long long total)
{
    long long gid = (long long)blockIdx.x * 256 + threadIdx.x;
    if (gid >= total) return;
    int e = (int)(gid >> 6);
    int f = (int)(gid & 63);
    int r = clampi(rows[e], n), c = clampi(cols[e], n);
    atomicAdd(&agg[(long long)c * FDIM + f], src[(long long)r * FDIM + f]);
    if (f == 0) atomicAdd(&deg[c], 1.0f);
}

template <bool RELU, bool NORM>
__global__ __launch_bounds__(256) void dense_kernel(
    const float* __restrict__ agg, const float* __restrict__ deg, const float* __restrict__ x,
    const float* __restrict__ W, const float* __restrict__ b,
    const float* __restrict__ R, float* __restrict__ out, int n)
{
    __shared__ float Ws[FDIM][FDIM];
    __shared__ float Rs[FDIM][FDIM];
    __shared__ float bs[FDIM];
    __shared__ float aRow[4][FDIM];
    __shared__ float xRow[4][FDIM];
    int tid = threadIdx.x;
    for (int i = tid; i < FDIM * FDIM; i += 256) {
        Ws[i >> 6][i & 63] = W[i];
        Rs[i >> 6][i & 63] = R[i];
    }
    if (tid < FDIM) bs[tid] = b[tid];
    int j = tid & 63, r = tid >> 6;
    int row = blockIdx.x * 4 + r;
    if (row < n) {
        float d = fmaxf(deg[row], 1.0f);
        aRow[r][j] = agg[(long long)row * FDIM + j] / d;
        xRow[r][j] = x[(long long)row * FDIM + j];
    }
    __syncthreads();
    if (row >= n) return;
    float acc = bs[j];
#pragma unroll
    for (int k = 0; k < FDIM; ++k)
        acc = fmaf(aRow[r][k], Ws[k][j], fmaf(xRow[r][k], Rs[k][j], acc));
    if (RELU) acc = fmaxf(acc, 0.0f);
    if (NORM) {
        float ss = acc * acc;
#pragma unroll
        for (int o = 32; o; o >>= 1) ss += __shfl_xor(ss, o, 64);
        acc *= 1.0f / fmaxf(sqrtf(ss), 1e-12f);
    }
    out[(long long)row * FDIM + j] = acc;
}

// ---------------------------------------------------------------------------
extern "C" void kernel_launch(void* const* d_in, const int* in_sizes, int n_in,
                              void* d_out, int out_size, void* d_ws, size_t ws_size,
                              hipStream_t stream)
{
    const float* x  = (const float*)d_in[0];
    const int*   e0 = (const int*)d_in[1];
    const int*   e1 = (const int*)d_in[2];
    const float* W1 = (const float*)d_in[3];
    const float* b1 = (const float*)d_in[4];
    const float* R1 = (const float*)d_in[5];
    const float* W2 = (const float*)d_in[6];
    const float* b2 = (const float*)d_in[7];
    const float* R2 = (const float*)d_in[8];
    float* out = (float*)d_out;

    const int N = in_sizes[0] / FDIM;     // 50000
    const int E = in_sizes[1] / 2;        // 1600000
    const int halfN = N >> 1;             // source-tile boundary

    const int nb = (N + BKT_NODES - 1) >> BKT_SHIFT;
    const int chunk = (E + NBLK_G - 1) / NBLK_G;
    const int GATHER_BLOCKS = 2048;       // 1 KB LDS, VGPR ~80
    const int GEMM_BLOCKS = 1024;         // ~12 rows/wave, amortizes reg-W load

    // Workspace (16-B aligned), both layers' CSR live simultaneously:
    // pairs1[2E] u32 | csridx[2E] u16 | blockcnt[2*NBLK_G*nb] |
    // startsTbl[2*NBLK_G*nb] | bucketTot[2*nb] | rowptr[2*(2N+1)] |
    // P16[N*64] half   (~29 MB)
    auto align16 = [](size_t v) { return (v + 15) & ~(size_t)15; };
    size_t off = 0;
    size_t o_pairs1 = off; off = align16(off + (size_t)2 * E * 4);
    size_t o_csr16  = off; off = align16(off + (size_t)2 * E * 2);
    size_t o_bcnt   = off; off = align16(off + (size_t)2 * NBLK_G * nb * 4);
    size_t o_stbl   = off; off = align16(off + (size_t)2 * NBLK_G * nb * 4);
    size_t o_btot   = off; off = align16(off + (size_t)2 * nb * 4);
    size_t o_rowp   = off; off = align16(off + (size_t)2 * (2 * N + 1) * 4);
    size_t o_p16    = off; off = align16(off + (size_t)N * FDIM * 2);
    const size_t need1 = off;

    const bool ok1 = (ws_size >= need1) && (N <= 65536) &&
                     (chunk <= CHUNK_CAP) && (nb <= NB_MAX);

    if (ok1) {
        char* wsb = (char*)d_ws;
        unsigned*        pairs1     = (unsigned*)(wsb + o_pairs1);
        unsigned short*  csridx     = (unsigned short*)(wsb + o_csr16);
        int*             blockcnt   = (int*)(wsb + o_bcnt);
        int*             startsTbl  = (int*)(wsb + o_stbl);
        int*             bucketTot  = (int*)(wsb + o_btot);
        int*             rowptr     = (int*)(wsb + o_rowp);
        __half*          P16        = (__half*)(wsb + o_p16);
        const int*       rowptr0    = rowptr;
        const int*       rowptr1    = rowptr + (2 * N + 1);
        const unsigned short* csridx0 = csridx;
        const unsigned short* csridx1 = csridx + (size_t)E;

        hipMemsetAsync(bucketTot, 0, (size_t)2 * nb * sizeof(int), stream);

        // ---- Layer 1 GEMM: P16 = x@W1 (fp16), Q1 = x@R1 + b1 -> out ----
        gemm_pq_kernel<<<GEMM_BLOCKS, 256, 0, stream>>>(
            x, W1, R1, b1, P16, out, N);

        // ---- CSR build for BOTH layers (merged launches, 1-round p4) ----
        p1_bin_stage<<<2 * NBLK_G, 512, 0, stream>>>(
            e0, e0 + E, e1, e1 + E, pairs1, blockcnt, startsTbl, bucketTot,
            N, E, nb, chunk);
        p4_fine2<<<2 * nb, 512, 0, stream>>>(
            pairs1, blockcnt, startsTbl, bucketTot, rowptr, csridx,
            N, E, nb, chunk, NBLK_G, halfN);

        // ---- Layer 1 gather: two source-tiled passes, relu on pass B ----
        fused_gather_kernel<0, false, false><<<GATHER_BLOCKS, 256, 0, stream>>>(
            rowptr0, csridx0, P16, out, N);
        fused_gather_kernel<1, true, false><<<GATHER_BLOCKS, 256, 0, stream>>>(
            rowptr0, csridx0, P16, out, N);

        // ---- Layer 2 GEMM: P16 = h@W2, Q2 = h@R2 + b2 (in-place) ----
        gemm_pq_kernel<<<GEMM_BLOCKS, 256, 0, stream>>>(
            out, W2, R2, b2, P16, out, N);

        // ---- Layer 2 gather: two passes, normalize on pass B ----
        fused_gather_kernel<0, false, false><<<GATHER_BLOCKS, 256, 0, stream>>>(
            rowptr1, csridx1, P16, out, N);
        fused_gather_kernel<1, false, true><<<GATHER_BLOCKS, 256, 0, stream>>>(
            rowptr1, csridx1, P16, out, N);
    } else {
        // Fallback: atomic scatter path (round-3, verified)
        float* agg = (float*)d_ws;
        float* deg = agg + (long long)N * FDIM;
        float* h = out;
        const long long total = (long long)E * FDIM;
        const int sblocks = (int)((total + 255) / 256);
        const int dblocks = (N + 3) / 4;

        hipMemsetAsync(agg, 0, ((size_t)N * FDIM + N) * sizeof(float), stream);
        scatter_kernel<<<sblocks, 256, 0, stream>>>(x, e0, e0 + E, agg, deg, N, total);
        dense_kernel<true, false><<<dblocks, 256, 0, stream>>>(agg, deg, x, W1, b1, R1, h, N);

        hipMemsetAsync(agg, 0, ((size_t)N * FDIM + N) * sizeof(float), stream);
        scatter_kernel<<<sblocks, 256, 0, stream>>>(h, e1, e1 + E, agg, deg, N, total);
        dense_kernel<false, true><<<dblocks, 256, 0, stream>>>(agg, deg, h, W2, b2, R2, out, N);
    }
}

// Round 10
// 260.290 us; speedup vs baseline: 1.1261x; 1.1261x over previous
//
#include <hip/hip_runtime.h>
#include <hip/hip_bf16.h>
#include <hip/hip_fp16.h>

#define FDIM 64

// Bucketed CSR build parameters
#define NBLK_G 256        // chunks per layer for p1
#define CHUNK_CAP 8192    // max edges per chunk block (32 KB LDS stage)
#define BKT_SHIFT 7
#define BKT_NODES 128     // dest nodes per bucket
#define NB_MAX 512        // max buckets (N <= 65536)
#define STCAP 8192        // P4 LDS stage cap (edges)

__device__ __forceinline__ int clampi(int v, int n) { return min(max(v, 0), n - 1); }

// ---- P1 (both layers): block-local bin + contiguous stage + counts --------
// grid = 2*NBLK_G; blocks [0,NBLK_G) do layer 0, rest layer 1. (R7-verified)
// Accumulates global bucketTot via atomics; bucketTot zeroed before launch.
__global__ __launch_bounds__(512) void p1_bin_stage(
    const int* __restrict__ r0, const int* __restrict__ c0,
    const int* __restrict__ r1, const int* __restrict__ c1,
    unsigned* __restrict__ pairs1, int* __restrict__ blockcnt,
    int* __restrict__ startsTbl, int* __restrict__ bucketTot,
    int n, int E, int nb, int chunk)
{
    __shared__ unsigned stage[CHUNK_CAP];
    __shared__ int hist[NB_MAX];
    __shared__ int curs[NB_MAX];
    int layer = blockIdx.x / NBLK_G;
    int cb = blockIdx.x - layer * NBLK_G;
    const int* rows = layer ? r1 : r0;
    const int* cols = layer ? c1 : c0;
    pairs1    += (size_t)layer * E;
    blockcnt  += (size_t)layer * NBLK_G * nb;
    startsTbl += (size_t)layer * NBLK_G * nb;
    bucketTot += layer * nb;

    int tid = threadIdx.x;
    int base = cb * chunk;
    int cnt = E - base; if (cnt > chunk) cnt = chunk; if (cnt < 0) cnt = 0;
    for (int i = tid; i < NB_MAX; i += 512) hist[i] = 0;
    __syncthreads();
    for (int i = tid; i < cnt; i += 512)
        atomicAdd(&hist[clampi(cols[base + i], n) >> BKT_SHIFT], 1);
    __syncthreads();
    for (int b = tid; b < nb; b += 512) {
        int hv = hist[b];
        blockcnt[cb * nb + b] = hv;
        if (hv) atomicAdd(&bucketTot[b], hv);   // global bucket totals
    }
    __syncthreads();
    for (int off = 1; off < NB_MAX; off <<= 1) {
        int t = (tid >= off) ? hist[tid - off] : 0;
        __syncthreads();
        hist[tid] += t;
        __syncthreads();
    }
    curs[tid] = (tid == 0) ? 0 : hist[tid - 1];
    __syncthreads();
    // persist chunk-local exclusive starts BEFORE atomics mutate curs
    for (int b = tid; b < nb; b += 512) startsTbl[cb * nb + b] = curs[b];
    __syncthreads();
    for (int i = tid; i < cnt; i += 512) {
        int c = clampi(cols[base + i], n);
        int r = clampi(rows[base + i], n);
        int p = atomicAdd(&curs[c >> BKT_SHIFT], 1);
        stage[p] = ((unsigned)r << 16) | (unsigned)c;
    }
    __syncthreads();
    for (int i = tid; i < cnt; i += 512) pairs1[base + i] = stage[i];
}

// ---- P4 (both layers, 512 threads): per-bucket fine CSR (R7-verified) ------
// grid = 2*nb single launch; ~36.5 KB LDS -> 4 blocks/CU so 782 blocks
// complete in ONE round. Self-contained scans; stage copy 2 threads/chunk.
__global__ __launch_bounds__(512) void p4_fine2(
    const unsigned* __restrict__ pairs1, const int* __restrict__ blockcnt,
    const int* __restrict__ startsTbl, const int* __restrict__ bucketTot,
    int* __restrict__ rowptr, unsigned short* __restrict__ csridx,
    int n, int E, int nb, int chunk, int nblk)
{
    __shared__ unsigned st[STCAP];
    __shared__ int h[BKT_NODES];
    __shared__ int cur[BKT_NODES];
    __shared__ int bscan[NB_MAX];    // inclusive scan of bucketTot (512 wide)
    __shared__ int colv[NBLK_G];     // inclusive scan of this bucket's column
    int tid = threadIdx.x;
    int layer = blockIdx.x / nb;
    int b = blockIdx.x - layer * nb;
    pairs1    += (size_t)layer * E;
    blockcnt  += (size_t)layer * NBLK_G * nb;
    startsTbl += (size_t)layer * NBLK_G * nb;
    bucketTot += layer * nb;
    rowptr    += layer * (n + 1);
    csridx    += (size_t)layer * E;

    bscan[tid] = (tid < nb) ? bucketTot[tid] : 0;
    if (tid < NBLK_G) {
        int myc = (tid < nblk) ? blockcnt[(size_t)tid * nb + b] : 0;
        colv[tid] = myc;
    }
    if (tid < BKT_NODES) h[tid] = 0;
    __syncthreads();
    // fused Hillis-Steele: 512-wide on bscan, 256-wide on colv
    for (int off = 1; off < NB_MAX; off <<= 1) {
        int t0 = (tid >= off) ? bscan[tid - off] : 0;
        int t2 = (tid < NBLK_G && off < NBLK_G && tid >= off) ? colv[tid - off] : 0;
        __syncthreads();
        bscan[tid] += t0;
        if (tid < NBLK_G && off < NBLK_G) colv[tid] += t2;
        __syncthreads();
    }
    int beg = (b == 0) ? 0 : bscan[b - 1];
    int cnt = bscan[b] - beg;

    bool fit = (cnt <= STCAP);       // block-uniform -> in-branch barriers legal
    if (fit) {
        // 2 threads per chunk: tid&255 = chunk, tid>>8 = half
        int ch = tid & (NBLK_G - 1);
        int half = tid >> 8;
        if (ch < nblk) {
            int ccnt = E - ch * chunk; if (ccnt > chunk) ccnt = chunk; if (ccnt < 0) ccnt = 0;
            int stt = startsTbl[(size_t)ch * nb + b];
            int enn = (b + 1 < nb) ? startsTbl[(size_t)ch * nb + b + 1] : ccnt;
            int len = enn - stt;
            int dst = (ch == 0) ? 0 : colv[ch - 1];      // exclusive offset
            int h0 = (len + 1) >> 1;
            int jb = half ? (stt + h0) : stt;
            int je = half ? enn : (stt + h0);
            int db = half ? (dst + h0) : dst;
            const unsigned* srcp = pairs1 + (size_t)ch * chunk;
            for (int j = jb; j < je; ++j)
                st[db + (j - jb)] = srcp[j];
        }
        __syncthreads();
        for (int i = tid; i < cnt; i += 512)
            atomicAdd(&h[st[i] & (BKT_NODES - 1)], 1);
    } else {
        for (int i = tid; i < nblk; i += 512) {
            int ccnt = E - i * chunk; if (ccnt > chunk) ccnt = chunk; if (ccnt < 0) ccnt = 0;
            int stt = startsTbl[(size_t)i * nb + b];
            int enn = (b + 1 < nb) ? startsTbl[(size_t)i * nb + b + 1] : ccnt;
            for (int j = stt; j < enn; ++j)
                atomicAdd(&h[pairs1[(size_t)i * chunk + j] & (BKT_NODES - 1)], 1);
        }
    }
    // barrier between histogram atomics and scan (round-9 race fix)
    __syncthreads();
    for (int off = 1; off < BKT_NODES; off <<= 1) {
        int t = (tid >= off && tid < BKT_NODES) ? h[tid - off] : 0;
        __syncthreads();
        if (tid < BKT_NODES) h[tid] += t;
        __syncthreads();
    }
    if (tid < BKT_NODES) {
        int node = b * BKT_NODES + tid;
        int startl = (tid == 0) ? 0 : h[tid - 1];
        cur[tid] = startl;
        if (node < n) rowptr[node] = beg + startl;
    }
    __syncthreads();
    if (fit) {
        for (int i = tid; i < cnt; i += 512) {
            unsigned pk = st[i];
            int p = atomicAdd(&cur[pk & (BKT_NODES - 1)], 1);
            csridx[beg + p] = (unsigned short)(pk >> 16);
        }
    } else {
        for (int i = tid; i < nblk; i += 512) {
            int ccnt = E - i * chunk; if (ccnt > chunk) ccnt = chunk; if (ccnt < 0) ccnt = 0;
            int stt = startsTbl[(size_t)i * nb + b];
            int enn = (b + 1 < nb) ? startsTbl[(size_t)i * nb + b + 1] : ccnt;
            for (int j = stt; j < enn; ++j) {
                unsigned pk = pairs1[(size_t)i * chunk + j];
                int p = atomicAdd(&cur[pk & (BKT_NODES - 1)], 1);
                csridx[beg + p] = (unsigned short)(pk >> 16);
            }
        }
    }
    if (b == nb - 1 && tid == 0) rowptr[n] = E;
}

// ------ GEMM precompute: P = src@W (fp16), Q = src@R + b (fp32) -------------
// mean-agg is linear, so agg(x)@W == agg(x@W). Weights register-resident;
// per-row broadcast via v_readlane. Q32 may alias src (wave reads its row
// before writing; rows are wave-disjoint).
__global__ __launch_bounds__(256) void gemm_pq_kernel(
    const float* __restrict__ src, const float* __restrict__ W,
    const float* __restrict__ R, const float* __restrict__ bvec,
    __half* __restrict__ P16, float* __restrict__ Q32, int n)
{
    int lane = threadIdx.x & 63;
    int wv = threadIdx.x >> 6;
    float wcol[FDIM], rcol[FDIM];
#pragma unroll
    for (int k = 0; k < FDIM; ++k) {
        wcol[k] = W[k * FDIM + lane];   // coalesced: lane j reads W[k][j]
        rcol[k] = R[k * FDIM + lane];
    }
    float bj = bvec[lane];
    for (int row = blockIdx.x * 4 + wv; row < n; row += gridDim.x * 4) {
        float xv = src[((size_t)row << 6) + lane];
        float accP = 0.0f, accQ = bj;
#pragma unroll
        for (int k = 0; k < FDIM; ++k) {
            float s = __uint_as_float(
                __builtin_amdgcn_readlane(__float_as_uint(xv), k));
            accP = fmaf(s, wcol[k], accP);
            accQ = fmaf(s, rcol[k], accQ);
        }
        P16[((size_t)row << 6) + lane] = __float2half(accP);
        Q32[((size_t)row << 6) + lane] = accQ;
    }
}

// ------ Fused gather (R8-verified): out = act(mean-gather(P16) + Q) ---------
// 8 lanes x float4 (16 B) per 128-B edge row; 4 steps' shfl+loads batched
// before accumulating. Q (out32[node]) hoisted above the edge loop.
template <bool RELU, bool NORM>
__global__ __launch_bounds__(256) void fused_gather_kernel(
    const int* __restrict__ rowptr, const unsigned short* __restrict__ csridx,
    const __half* __restrict__ P16, float* __restrict__ out32, int n)
{
    __shared__ __align__(16) float aRow[4][FDIM];
    int tid = threadIdx.x;
    int lane = tid & 63, w = tid >> 6;
    int g = lane >> 3;        // edge sub-group 0..7
    int q = lane & 7;         // 8-feature chunk within row

    for (int node = blockIdx.x * 4 + w; node < n; node += gridDim.x * 4) {
        int beg = rowptr[node], end = rowptr[node + 1];
        float ownv = out32[((size_t)node << 6) + lane];   // prefetch Q early
        float s0 = 0.f, s1 = 0.f, s2 = 0.f, s3 = 0.f,
              s4 = 0.f, s5 = 0.f, s6 = 0.f, s7 = 0.f;
        for (int base = beg; base < end; base += 64) {
            int cnt = end - base; if (cnt > 64) cnt = 64;
            int ei = base + lane;
            int myidx = (ei < end) ? (int)csridx[ei] : 0;
            for (int t4 = 0; t4 < 64; t4 += 32) {
                if (t4 >= cnt) break;
                int sidx[4];
                float4 v[4];
#pragma unroll
                for (int u = 0; u < 4; ++u)
                    sidx[u] = __shfl(myidx, t4 | (u << 3) | g, 64);
#pragma unroll
                for (int u = 0; u < 4; ++u) {
                    int e = t4 | (u << 3) | g;
                    v[u] = make_float4(0.f, 0.f, 0.f, 0.f);
                    if (e < cnt)
                        v[u] = *((const float4*)(P16 + ((size_t)sidx[u] << 6)) + q);
                }
#pragma unroll
                for (int u = 0; u < 4; ++u) {
                    const __half2* hp = (const __half2*)&v[u];
                    float2 f0 = __half22float2(hp[0]);
                    float2 f1 = __half22float2(hp[1]);
                    float2 f2 = __half22float2(hp[2]);
                    float2 f3 = __half22float2(hp[3]);
                    s0 += f0.x; s1 += f0.y; s2 += f1.x; s3 += f1.y;
                    s4 += f2.x; s5 += f2.y; s6 += f3.x; s7 += f3.y;
                }
            }
        }
#pragma unroll
        for (int o = 8; o < 64; o <<= 1) {
            s0 += __shfl_xor(s0, o, 64);
            s1 += __shfl_xor(s1, o, 64);
            s2 += __shfl_xor(s2, o, 64);
            s3 += __shfl_xor(s3, o, 64);
            s4 += __shfl_xor(s4, o, 64);
            s5 += __shfl_xor(s5, o, 64);
            s6 += __shfl_xor(s6, o, 64);
            s7 += __shfl_xor(s7, o, 64);
        }
        float dinv = 1.0f / fmaxf((float)(end - beg), 1.0f);
        if (g == 0) {
            float4* ar = (float4*)&aRow[w][q * 8];
            ar[0] = make_float4(s0 * dinv, s1 * dinv, s2 * dinv, s3 * dinv);
            ar[1] = make_float4(s4 * dinv, s5 * dinv, s6 * dinv, s7 * dinv);
        }
        // wave-local LDS RAW: ordered within the wave, no barrier needed
        float acc = aRow[w][lane] + ownv;
        if (RELU) acc = fmaxf(acc, 0.0f);
        if (NORM) {
            float ss = acc * acc;
#pragma unroll
            for (int o = 32; o; o >>= 1) ss += __shfl_xor(ss, o, 64);
            acc *= 1.0f / fmaxf(sqrtf(ss), 1e-12f);
        }
        out32[((size_t)node << 6) + lane] = acc;
    }
}

// ----------------- Atomic scatter path (fallback, 13.0 MB ws) ---------------
__global__ __launch_bounds__(256) void scatter_kernel(
    const float* __restrict__ src, const int* __restrict__ rows, const int* __restrict__ cols,
    float* __restrict__ agg, float* __restrict__ deg, int n, long long total)
{
    long long gid = (long long)blockIdx.x * 256 + threadIdx.x;
    if (gid >= total) return;
    int e = (int)(gid >> 6);
    int f = (int)(gid & 63);
    int r = clampi(rows[e], n), c = clampi(cols[e], n);
    atomicAdd(&agg[(long long)c * FDIM + f], src[(long long)r * FDIM + f]);
    if (f == 0) atomicAdd(&deg[c], 1.0f);
}

template <bool RELU, bool NORM>
__global__ __launch_bounds__(256) void dense_kernel(
    const float* __restrict__ agg, const float* __restrict__ deg, const float* __restrict__ x,
    const float* __restrict__ W, const float* __restrict__ b,
    const float* __restrict__ R, float* __restrict__ out, int n)
{
    __shared__ float Ws[FDIM][FDIM];
    __shared__ float Rs[FDIM][FDIM];
    __shared__ float bs[FDIM];
    __shared__ float aRow[4][FDIM];
    __shared__ float xRow[4][FDIM];
    int tid = threadIdx.x;
    for (int i = tid; i < FDIM * FDIM; i += 256) {
        Ws[i >> 6][i & 63] = W[i];
        Rs[i >> 6][i & 63] = R[i];
    }
    if (tid < FDIM) bs[tid] = b[tid];
    int j = tid & 63, r = tid >> 6;
    int row = blockIdx.x * 4 + r;
    if (row < n) {
        float d = fmaxf(deg[row], 1.0f);
        aRow[r][j] = agg[(long long)row * FDIM + j] / d;
        xRow[r][j] = x[(long long)row * FDIM + j];
    }
    __syncthreads();
    if (row >= n) return;
    float acc = bs[j];
#pragma unroll
    for (int k = 0; k < FDIM; ++k)
        acc = fmaf(aRow[r][k], Ws[k][j], fmaf(xRow[r][k], Rs[k][j], acc));
    if (RELU) acc = fmaxf(acc, 0.0f);
    if (NORM) {
        float ss = acc * acc;
#pragma unroll
        for (int o = 32; o; o >>= 1) ss += __shfl_xor(ss, o, 64);
        acc *= 1.0f / fmaxf(sqrtf(ss), 1e-12f);
    }
    out[(long long)row * FDIM + j] = acc;
}

// ---------------------------------------------------------------------------
extern "C" void kernel_launch(void* const* d_in, const int* in_sizes, int n_in,
                              void* d_out, int out_size, void* d_ws, size_t ws_size,
                              hipStream_t stream)
{
    const float* x  = (const float*)d_in[0];
    const int*   e0 = (const int*)d_in[1];
    const int*   e1 = (const int*)d_in[2];
    const float* W1 = (const float*)d_in[3];
    const float* b1 = (const float*)d_in[4];
    const float* R1 = (const float*)d_in[5];
    const float* W2 = (const float*)d_in[6];
    const float* b2 = (const float*)d_in[7];
    const float* R2 = (const float*)d_in[8];
    float* out = (float*)d_out;

    const int N = in_sizes[0] / FDIM;     // 50000
    const int E = in_sizes[1] / 2;        // 1600000

    const int nb = (N + BKT_NODES - 1) >> BKT_SHIFT;
    const int chunk = (E + NBLK_G - 1) / NBLK_G;
    const int GATHER_BLOCKS = 2048;       // 1 KB LDS, VGPR ~80
    const int GEMM_BLOCKS = 1024;         // ~12 rows/wave, amortizes reg-W load

    // Workspace (16-B aligned), both layers' CSR live simultaneously:
    // pairs1[2E] u32 | csridx[2E] u16 | blockcnt[2*NBLK_G*nb] |
    // startsTbl[2*NBLK_G*nb] | bucketTot[2*nb] | rowptr[2*(N+1)] |
    // P16[N*64] half   (~28 MB)
    auto align16 = [](size_t v) { return (v + 15) & ~(size_t)15; };
    size_t off = 0;
    size_t o_pairs1 = off; off = align16(off + (size_t)2 * E * 4);
    size_t o_csr16  = off; off = align16(off + (size_t)2 * E * 2);
    size_t o_bcnt   = off; off = align16(off + (size_t)2 * NBLK_G * nb * 4);
    size_t o_stbl   = off; off = align16(off + (size_t)2 * NBLK_G * nb * 4);
    size_t o_btot   = off; off = align16(off + (size_t)2 * nb * 4);
    size_t o_rowp   = off; off = align16(off + (size_t)2 * (N + 1) * 4);
    size_t o_p16    = off; off = align16(off + (size_t)N * FDIM * 2);
    const size_t need1 = off;

    const bool ok1 = (ws_size >= need1) && (N <= 65536) &&
                     (chunk <= CHUNK_CAP) && (nb <= NB_MAX);

    if (ok1) {
        char* wsb = (char*)d_ws;
        unsigned*        pairs1     = (unsigned*)(wsb + o_pairs1);
        unsigned short*  csridx     = (unsigned short*)(wsb + o_csr16);
        int*             blockcnt   = (int*)(wsb + o_bcnt);
        int*             startsTbl  = (int*)(wsb + o_stbl);
        int*             bucketTot  = (int*)(wsb + o_btot);
        int*             rowptr     = (int*)(wsb + o_rowp);
        __half*          P16        = (__half*)(wsb + o_p16);
        const int*       rowptr0    = rowptr;
        const int*       rowptr1    = rowptr + (N + 1);
        const unsigned short* csridx0 = csridx;
        const unsigned short* csridx1 = csridx + (size_t)E;

        hipMemsetAsync(bucketTot, 0, (size_t)2 * nb * sizeof(int), stream);

        // ---- Layer 1 GEMM: P16 = x@W1 (fp16), Q1 = x@R1 + b1 -> out ----
        gemm_pq_kernel<<<GEMM_BLOCKS, 256, 0, stream>>>(
            x, W1, R1, b1, P16, out, N);

        // ---- CSR build for BOTH layers (merged launches, 1-round p4) ----
        p1_bin_stage<<<2 * NBLK_G, 512, 0, stream>>>(
            e0, e0 + E, e1, e1 + E, pairs1, blockcnt, startsTbl, bucketTot,
            N, E, nb, chunk);
        p4_fine2<<<2 * nb, 512, 0, stream>>>(
            pairs1, blockcnt, startsTbl, bucketTot, rowptr, csridx,
            N, E, nb, chunk, NBLK_G);

        // ---- Layer 1 gather: h = relu(mean-gather(P1) + Q1), in place ----
        fused_gather_kernel<true, false><<<GATHER_BLOCKS, 256, 0, stream>>>(
            rowptr0, csridx0, P16, out, N);

        // ---- Layer 2 GEMM: P16 = h@W2, Q2 = h@R2 + b2 (in-place) ----
        gemm_pq_kernel<<<GEMM_BLOCKS, 256, 0, stream>>>(
            out, W2, R2, b2, P16, out, N);

        // ---- Layer 2 gather: out = normalize(mean-gather(P2) + Q2) ----
        fused_gather_kernel<false, true><<<GATHER_BLOCKS, 256, 0, stream>>>(
            rowptr1, csridx1, P16, out, N);
    } else {
        // Fallback: atomic scatter path (round-3, verified)
        float* agg = (float*)d_ws;
        float* deg = agg + (long long)N * FDIM;
        float* h = out;
        const long long total = (long long)E * FDIM;
        const int sblocks = (int)((total + 255) / 256);
        const int dblocks = (N + 3) / 4;

        hipMemsetAsync(agg, 0, ((size_t)N * FDIM + N) * sizeof(float), stream);
        scatter_kernel<<<sblocks, 256, 0, stream>>>(x, e0, e0 + E, agg, deg, N, total);
        dense_kernel<true, false><<<dblocks, 256, 0, stream>>>(agg, deg, x, W1, b1, R1, h, N);

        hipMemsetAsync(agg, 0, ((size_t)N * FDIM + N) * sizeof(float), stream);
        scatter_kernel<<<sblocks, 256, 0, stream>>>(h, e1, e1 + E, agg, deg, N, total);
        dense_kernel<false, true><<<dblocks, 256, 0, stream>>>(agg, deg, h, W2, b2, R2, out, N);
    }
}